// Round 15
// baseline (419.907 us; speedup 1.0000x reference)
//
#include <hip/hip_runtime.h>

typedef _Float16 half8 __attribute__((ext_vector_type(8)));
typedef float f32x4 __attribute__((ext_vector_type(4)));

static constexpr int D = 1024;       // VQ_C == C_IN
static constexpr int NCODE = 2048;   // codebook size
static constexpr int MTOK = 16384;   // B * L = 8 * 2048
static constexpr int KIN = 2048;     // C_IN * DS
static constexpr int TLEN = 4096;
static constexpr int CAP = 2048;     // max rescored tokens (est. ~250 flagged)
#define TAU 0.4f

__device__ __forceinline__ void gload16(const void* g, void* l) {
  __builtin_amdgcn_global_load_lds(
      (const __attribute__((address_space(1))) void*)g,
      (__attribute__((address_space(3))) void*)l, 16, 0, 0);
}

#define SBAR()   asm volatile("s_barrier" ::: "memory")
#define WAITV8() asm volatile("s_waitcnt vmcnt(8)" ::: "memory")
#define WAITV4() asm volatile("s_waitcnt vmcnt(4)" ::: "memory")
#define WAITV0() asm volatile("s_waitcnt vmcnt(0)" ::: "memory")

__device__ __forceinline__ float key_to_f32(unsigned u) {
  unsigned bits = (u & 0x80000000u) ? (u & 0x7FFFFFFFu) : ~u;
  return __uint_as_float(bits);
}
__device__ __forceinline__ unsigned f32_to_key(float f) {
  unsigned ub = __float_as_uint(f);
  return (ub & 0x80000000u) ? ~ub : (ub | 0x80000000u);
}

// ---------------- pack kernels ----------------
__global__ __launch_bounds__(256) void k_pack_x(const float* __restrict__ x,
                                                _Float16* __restrict__ xh,
                                                _Float16* __restrict__ xl) {
  __shared__ float lds[32][65];
  const int tt0 = blockIdx.x * 64;
  const int cc0 = blockIdx.y * 32;
  const int b = blockIdx.z;
  const float* xb = x + ((size_t)b * D + cc0) * TLEN + tt0;
#pragma unroll
  for (int i = 0; i < 8; ++i) {
    int idx = threadIdx.x + i * 256;
    lds[idx >> 6][idx & 63] = xb[(size_t)(idx >> 6) * TLEN + (idx & 63)];
  }
  __syncthreads();
  const size_t mrow0 = (size_t)b * 2048 + (tt0 >> 1);
  const int r = threadIdx.x >> 3;
  const int g = threadIdx.x & 7;
  half8 vh, vl;
#pragma unroll
  for (int j = 0; j < 8; ++j) {
    int kk = g * 8 + j;
    float v = lds[kk >> 1][2 * r + (kk & 1)];
    _Float16 h = (_Float16)v;
    vh[j] = h;
    vl[j] = (_Float16)(v - (float)h);
  }
  size_t off = (mrow0 + r) * (size_t)KIN + (size_t)cc0 * 2 + g * 8;
  *(half8*)(xh + off) = vh;
  *(half8*)(xl + off) = vl;
}

// merged splitter: w_in -> wh/wl, embed -> eh/el, w_out -> woh (hi only)
__global__ __launch_bounds__(256) void k_split3(
    const float* __restrict__ w_in, const float* __restrict__ embed,
    const float* __restrict__ w_out,
    _Float16* __restrict__ wh, _Float16* __restrict__ wl,
    _Float16* __restrict__ eh, _Float16* __restrict__ el,
    _Float16* __restrict__ woh) {
  int i = blockIdx.x * 256 + threadIdx.x;
  if (i < D * KIN) {
    float v = w_in[i];
    _Float16 h = (_Float16)v;
    wh[i] = h;
    wl[i] = (_Float16)(v - (float)h);
  } else if (i < D * KIN + NCODE * D) {
    int j = i - D * KIN;
    float v = embed[j];
    _Float16 h = (_Float16)v;
    eh[j] = h;
    el[j] = (_Float16)(v - (float)h);
  } else if (i < D * KIN + NCODE * D + D * D) {
    int j = i - D * KIN - NCODE * D;
    woh[j] = (_Float16)w_out[j];
  }
}

// e2 + fold zero-inits (counter, lossacc, t2)
__global__ __launch_bounds__(256) void k_e2(const float* __restrict__ embed,
                                            float* __restrict__ e2c,
                                            int* __restrict__ counter,
                                            double* __restrict__ lossacc,
                                            float* __restrict__ t2) {
  if (blockIdx.x == 0 && threadIdx.x == 0) { counter[0] = 0; lossacc[0] = 0.0; }
  int g = blockIdx.x * 256 + threadIdx.x;
  if (g < MTOK) t2[g] = 0.f;
  int row = blockIdx.x * 4 + (threadIdx.x >> 6);
  int lane = threadIdx.x & 63;
  const float* er = embed + (size_t)row * D;
  double s = 0.0;
  for (int i = lane; i < D; i += 64) { double v = er[i]; s += v * v; }
#pragma unroll
  for (int mk = 1; mk < 64; mk <<= 1) s += __shfl_xor(s, mk, 64);
  if (lane == 0) e2c[row] = (float)(s - 1024.0);
}

// ---------------- hh GEMM: 256x256 tile, 512 thr, 8 waves (2x4), 4-buf 3-deep ------
// R15: prefetch depth 2->3 (4 buffers, 128KB, still 1 block/CU), counted vmcnt(8)
// in steady state (oldest tile landed, 2 tiles in flight), 8->4->0 tail drains.
// MODE 0: tok epilogue (bias, f16 hi store, ||t||^2 atomics).  MODE 1: score top-2.
template <int KDIM, int LOG_GX, int MODE>
__global__ __launch_bounds__(512, 2) void k_gemm_hh(
    const _Float16* __restrict__ Ah_, const _Float16* __restrict__ Bh_,
    const float* __restrict__ vec,
    _Float16* __restrict__ outh, float* __restrict__ t2,
    unsigned long long* __restrict__ skKey, float* __restrict__ skSnd) {
  __shared__ _Float16 lds[4 * 16384];  // 4 x 32KB
  const int nwg = gridDim.x, bid = blockIdx.x, q = nwg >> 3;
  const int b2 = (bid & 7) * q + (bid >> 3);
  const int nb = b2 & ((1 << LOG_GX) - 1);
  const int n0 = nb * 256, m0 = (b2 >> LOG_GX) * 256;
  const int tid = threadIdx.x, lane = tid & 63, w = tid >> 6;
  const int wr = w >> 2, wc = w & 3, lr = lane & 15, lk = lane >> 4;
  constexpr int NT = KDIM / 32;
  const int cswz8 = (((lane & 3) ^ ((lane >> 3) & 3))) * 8;
  const int rswz8 = (lk ^ ((lr >> 1) & 3)) * 8;

  f32x4 acc[8][4] = {};

  auto stage = [&](int t, int c) {  // 4 loads/thread = 32KB/block
    char* sb = (char*)(lds + c * 16384);
    const int k0 = t * 32;
    const int r0 = (w * 64 + lane) >> 2;
    gload16(Ah_ + (size_t)(m0 + r0) * KDIM + k0 + cswz8, sb + w * 1024);
    gload16(Ah_ + (size_t)(m0 + 128 + r0) * KDIM + k0 + cswz8, sb + w * 1024 + 8192);
    gload16(Bh_ + (size_t)(n0 + r0) * KDIM + k0 + cswz8, sb + 16384 + w * 1024);
    gload16(Bh_ + (size_t)(n0 + 128 + r0) * KDIM + k0 + cswz8, sb + 16384 + w * 1024 + 8192);
  };

  stage(0, 0);
  stage(1, 1);
  stage(2, 2);
  WAITV8();
  SBAR();

  for (int t = 0; t < NT; ++t) {
    const int c0 = t & 3;
    if (t + 3 < NT) stage(t + 3, (t + 3) & 3);
    const _Float16* sb = lds + c0 * 16384;
    half8 ah[8], bh[4];
#pragma unroll
    for (int f = 0; f < 8; ++f)
      ah[f] = *(const half8*)(sb + (wr * 128 + f * 16 + lr) * 32 + rswz8);
#pragma unroll
    for (int f = 0; f < 4; ++f)
      bh[f] = *(const half8*)(sb + 8192 + (wc * 64 + f * 16 + lr) * 32 + rswz8);
    __builtin_amdgcn_s_setprio(1);
#pragma unroll
    for (int fm = 0; fm < 8; ++fm)
#pragma unroll
      for (int fn = 0; fn < 4; ++fn)
        acc[fm][fn] = __builtin_amdgcn_mfma_f32_16x16x32_f16(ah[fm], bh[fn], acc[fm][fn], 0, 0, 0);
    __builtin_amdgcn_s_setprio(0);
    if (t + 3 < NT)      { WAITV8(); }
    else if (t + 2 < NT) { WAITV4(); }
    else if (t + 1 < NT) { WAITV0(); }
    SBAR();
  }

  if constexpr (MODE == 0) {
    // tok epilogue: +bias, store f16 hi, accumulate ||t||^2
#pragma unroll
    for (int fm = 0; fm < 8; ++fm) {
#pragma unroll
      for (int j = 0; j < 4; ++j) {
        int row = wr * 128 + fm * 16 + lk * 4 + j;
        size_t m = (size_t)m0 + row;
        float v2 = 0.f;
#pragma unroll
        for (int fn = 0; fn < 4; ++fn) {
          int col = n0 + wc * 64 + fn * 16 + lr;
          float v = acc[fm][fn][j] + vec[col];
          v2 += v * v;
          outh[m * (size_t)D + col] = (_Float16)v;
        }
#pragma unroll
        for (int mk = 1; mk < 16; mk <<= 1) v2 += __shfl_xor(v2, mk, 64);
        if (lr == 0) atomicAdd(&t2[m], v2);
      }
    }
  } else {
    // score epilogue: top-2 of mval over this wave's 64 codes -> slot nb*4+wc
#pragma unroll
    for (int fm = 0; fm < 8; ++fm) {
#pragma unroll
      for (int j = 0; j < 4; ++j) {
        int row = wr * 128 + fm * 16 + lk * 4 + j;
        size_t m = (size_t)m0 + row;
        float b1 = 3.4e38f, bb2 = 3.4e38f;
        int i1 = 0x7FFFFFFF;
#pragma unroll
        for (int fn = 0; fn < 4; ++fn) {
          int col = n0 + wc * 64 + fn * 16 + lr;
          float mv = vec[col] - 2.0f * acc[fm][fn][j];
          if (mv < b1) { bb2 = b1; b1 = mv; i1 = col; }
          else if (mv < bb2) { bb2 = mv; }
        }
#pragma unroll
        for (int mk = 1; mk < 16; mk <<= 1) {
          float ob1 = __shfl_xor(b1, mk, 64);
          float ob2 = __shfl_xor(bb2, mk, 64);
          int oi = __shfl_xor(i1, mk, 64);
          if (ob1 < b1) { bb2 = fminf(b1, ob2); b1 = ob1; i1 = oi; }
          else { bb2 = fminf(bb2, ob1); }
        }
        if (lr == 0) {
          unsigned long long key = ((unsigned long long)f32_to_key(b1) << 32) | (unsigned)i1;
          skKey[m * 32 + nb * 4 + wc] = key;
          skSnd[m * 32 + nb * 4 + wc] = bb2;
        }
      }
    }
  }
}

// ---------------- flag: global top-2 over 32 slots; also init keys2 ----------------
__global__ __launch_bounds__(256) void k_flag(const unsigned long long* __restrict__ skKey,
                                              const float* __restrict__ skSnd,
                                              unsigned long long* __restrict__ keys,
                                              unsigned long long* __restrict__ keys2,
                                              int* __restrict__ list, int* __restrict__ counter) {
  int m = blockIdx.x * 256 + threadIdx.x;
  keys2[m] = ~0ull;
  unsigned long long best = ~0ull;
  int bsl = 0;
#pragma unroll
  for (int sl = 0; sl < 32; ++sl) {
    unsigned long long k = skKey[(size_t)m * 32 + sl];
    if (k < best) { best = k; bsl = sl; }
  }
  float b1 = key_to_f32((unsigned)(best >> 32));
  float second = skSnd[(size_t)m * 32 + bsl];
#pragma unroll
  for (int sl = 0; sl < 32; ++sl) {
    if (sl != bsl) second = fminf(second, key_to_f32((unsigned)(skKey[(size_t)m * 32 + sl] >> 32)));
  }
  keys[m] = best;
  if (second - b1 < TAU) {
    int p = atomicAdd(counter, 1);
    if (p < CAP) list[p] = m;
  }
}

// ---------------- tok_fix: recompute TRUE tokens (3-product) for flagged rows ----------------
__global__ __launch_bounds__(256) void k_tok_fix(
    const _Float16* __restrict__ xh, const _Float16* __restrict__ xl,
    const _Float16* __restrict__ wh, const _Float16* __restrict__ wl,
    const float* __restrict__ b_in, const int* __restrict__ list,
    const int* __restrict__ counter,
    _Float16* __restrict__ tokh2, _Float16* __restrict__ tokl2) {
  const int count = min(counter[0], CAP);
  const int m0 = blockIdx.y * 128;
  if (m0 >= count) return;
  __shared__ _Float16 sAh[128 * 32], sAl[128 * 32], sBh[128 * 32], sBl[128 * 32];
  const int n0 = blockIdx.x * 128;
  const int tid = threadIdx.x, lane = tid & 63, w = tid >> 6;
  const int wr = w >> 1, wc = w & 1, lr = lane & 15, lk = lane >> 4;
  f32x4 acc[4][4] = {};

  const int g0 = w * 128 + lane, g1 = g0 + 64;
  const int rA0 = g0 >> 2, cA0 = g0 & 3, rA1 = g1 >> 2, cA1 = g1 & 3;
  const int lb0 = (w * 128) * 16, lb1 = (w * 128 + 64) * 16;
  const int tk0 = list[min(m0 + rA0, count - 1)];
  const int tk1 = list[min(m0 + rA1, count - 1)];

  for (int kt = 0; kt < KIN / 32; ++kt) {
    const int k0 = kt * 32;
    gload16(xh + (size_t)tk0 * KIN + k0 + cA0 * 8, (char*)sAh + lb0);
    gload16(xh + (size_t)tk1 * KIN + k0 + cA1 * 8, (char*)sAh + lb1);
    gload16(xl + (size_t)tk0 * KIN + k0 + cA0 * 8, (char*)sAl + lb0);
    gload16(xl + (size_t)tk1 * KIN + k0 + cA1 * 8, (char*)sAl + lb1);
    gload16(wh + (size_t)(n0 + rA0) * KIN + k0 + cA0 * 8, (char*)sBh + lb0);
    gload16(wh + (size_t)(n0 + rA1) * KIN + k0 + cA1 * 8, (char*)sBh + lb1);
    gload16(wl + (size_t)(n0 + rA0) * KIN + k0 + cA0 * 8, (char*)sBl + lb0);
    gload16(wl + (size_t)(n0 + rA1) * KIN + k0 + cA1 * 8, (char*)sBl + lb1);
    __syncthreads();
    half8 ah[4], al2[4], bh[4], bl2[4];
#pragma unroll
    for (int f = 0; f < 4; ++f) {
      ah[f]  = *(const half8*)(sAh + (wr * 64 + f * 16 + lr) * 32 + lk * 8);
      al2[f] = *(const half8*)(sAl + (wr * 64 + f * 16 + lr) * 32 + lk * 8);
      bh[f]  = *(const half8*)(sBh + (wc * 64 + f * 16 + lr) * 32 + lk * 8);
      bl2[f] = *(const half8*)(sBl + (wc * 64 + f * 16 + lr) * 32 + lk * 8);
    }
#pragma unroll
    for (int fm = 0; fm < 4; ++fm)
#pragma unroll
      for (int fn = 0; fn < 4; ++fn) {
        acc[fm][fn] = __builtin_amdgcn_mfma_f32_16x16x32_f16(ah[fm], bh[fn], acc[fm][fn], 0, 0, 0);
        acc[fm][fn] = __builtin_amdgcn_mfma_f32_16x16x32_f16(ah[fm], bl2[fn], acc[fm][fn], 0, 0, 0);
        acc[fm][fn] = __builtin_amdgcn_mfma_f32_16x16x32_f16(al2[fm], bh[fn], acc[fm][fn], 0, 0, 0);
      }
    __syncthreads();
  }
#pragma unroll
  for (int fm = 0; fm < 4; ++fm) {
#pragma unroll
    for (int j = 0; j < 4; ++j) {
      int row = wr * 64 + fm * 16 + lk * 4 + j;
      if (m0 + row >= count) continue;
#pragma unroll
      for (int fn = 0; fn < 4; ++fn) {
        int col = n0 + wc * 64 + fn * 16 + lr;
        float v = acc[fm][fn][j] + b_in[col];
        _Float16 h = (_Float16)v;
        tokh2[(size_t)(m0 + row) * D + col] = h;
        tokl2[(size_t)(m0 + row) * D + col] = (_Float16)(v - (float)h);
      }
    }
  }
}

// ---------------- rescore: 3-product exact scoring of flagged tokens ----------------
__global__ __launch_bounds__(256) void k_rescore(
    const _Float16* __restrict__ tokh2, const _Float16* __restrict__ tokl2,
    const _Float16* __restrict__ eh, const _Float16* __restrict__ el,
    const float* __restrict__ e2c, const int* __restrict__ list,
    const int* __restrict__ counter,
    unsigned long long* __restrict__ keys2) {
  const int count = min(counter[0], CAP);
  const int m0 = blockIdx.y * 128;
  if (m0 >= count) return;
  __shared__ _Float16 sAh[128 * 32], sAl[128 * 32], sBh[128 * 32], sBl[128 * 32];
  const int n0 = blockIdx.x * 128;
  const int tid = threadIdx.x, lane = tid & 63, w = tid >> 6;
  const int wr = w >> 1, wc = w & 1, lr = lane & 15, lk = lane >> 4;
  f32x4 acc[4][4] = {};

  const int g0 = w * 128 + lane, g1 = g0 + 64;
  const int rA0 = g0 >> 2, cA0 = g0 & 3, rA1 = g1 >> 2, cA1 = g1 & 3;
  const int lb0 = (w * 128) * 16, lb1 = (w * 128 + 64) * 16;

  for (int kt = 0; kt < D / 32; ++kt) {
    const int k0 = kt * 32;
    gload16(tokh2 + (size_t)(m0 + rA0) * D + k0 + cA0 * 8, (char*)sAh + lb0);
    gload16(tokh2 + (size_t)(m0 + rA1) * D + k0 + cA1 * 8, (char*)sAh + lb1);
    gload16(tokl2 + (size_t)(m0 + rA0) * D + k0 + cA0 * 8, (char*)sAl + lb0);
    gload16(tokl2 + (size_t)(m0 + rA1) * D + k0 + cA1 * 8, (char*)sAl + lb1);
    gload16(eh + (size_t)(n0 + rA0) * D + k0 + cA0 * 8, (char*)sBh + lb0);
    gload16(eh + (size_t)(n0 + rA1) * D + k0 + cA1 * 8, (char*)sBh + lb1);
    gload16(el + (size_t)(n0 + rA0) * D + k0 + cA0 * 8, (char*)sBl + lb0);
    gload16(el + (size_t)(n0 + rA1) * D + k0 + cA1 * 8, (char*)sBl + lb1);
    __syncthreads();
    half8 ah[4], al2[4], bh[4], bl2[4];
#pragma unroll
    for (int f = 0; f < 4; ++f) {
      ah[f]  = *(const half8*)(sAh + (wr * 64 + f * 16 + lr) * 32 + lk * 8);
      al2[f] = *(const half8*)(sAl + (wr * 64 + f * 16 + lr) * 32 + lk * 8);
      bh[f]  = *(const half8*)(sBh + (wc * 64 + f * 16 + lr) * 32 + lk * 8);
      bl2[f] = *(const half8*)(sBl + (wc * 64 + f * 16 + lr) * 32 + lk * 8);
    }
#pragma unroll
    for (int fm = 0; fm < 4; ++fm)
#pragma unroll
      for (int fn = 0; fn < 4; ++fn) {
        acc[fm][fn] = __builtin_amdgcn_mfma_f32_16x16x32_f16(ah[fm], bh[fn], acc[fm][fn], 0, 0, 0);
        acc[fm][fn] = __builtin_amdgcn_mfma_f32_16x16x32_f16(ah[fm], bl2[fn], acc[fm][fn], 0, 0, 0);
        acc[fm][fn] = __builtin_amdgcn_mfma_f32_16x16x32_f16(al2[fm], bh[fn], acc[fm][fn], 0, 0, 0);
      }
    __syncthreads();
  }
#pragma unroll
  for (int fm = 0; fm < 4; ++fm) {
#pragma unroll
    for (int j = 0; j < 4; ++j) {
      int row = wr * 64 + fm * 16 + lk * 4 + j;
      if (m0 + row >= count) continue;
      int tm = list[m0 + row];
      float best = 3.4e38f;
      int bidx = 0x7FFFFFFF;
#pragma unroll
      for (int fn = 0; fn < 4; ++fn) {
        int col = n0 + wc * 64 + fn * 16 + lr;
        float mv = e2c[col] - 2.0f * acc[fm][fn][j];
        if (mv < best) { best = mv; bidx = col; }
      }
#pragma unroll
      for (int mk = 1; mk < 16; mk <<= 1) {
        float ob = __shfl_xor(best, mk, 64);
        int oi = __shfl_xor(bidx, mk, 64);
        if (ob < best || (ob == best && oi < bidx)) { best = ob; bidx = oi; }
      }
      if (lr == 0) {
        unsigned long long key = ((unsigned long long)f32_to_key(best) << 32) | (unsigned)bidx;
        atomicMin(&keys2[tm], key);
      }
    }
  }
}

// ---------------- k_F: F = embed . w_out^T + b_out (hh-only) ----------------
__global__ __launch_bounds__(256) void k_F(
    const _Float16* __restrict__ eh, const _Float16* __restrict__ woh,
    const float* __restrict__ b_out, float* __restrict__ F) {
  __shared__ _Float16 sA[128 * 32], sB[128 * 32];
  const int n0 = blockIdx.x * 128, m0 = blockIdx.y * 128;
  const int tid = threadIdx.x, lane = tid & 63, w = tid >> 6;
  const int wr = w >> 1, wc = w & 1, lr = lane & 15, lk = lane >> 4;
  f32x4 acc[4][4] = {};

  const int g0 = w * 128 + lane, g1 = g0 + 64;
  const int rA0 = g0 >> 2, cA0 = g0 & 3, rA1 = g1 >> 2, cA1 = g1 & 3;
  const int lb0 = (w * 128) * 16, lb1 = (w * 128 + 64) * 16;

  for (int kt = 0; kt < D / 32; ++kt) {
    const int k0 = kt * 32;
    gload16(eh + (size_t)(m0 + rA0) * D + k0 + cA0 * 8, (char*)sA + lb0);
    gload16(eh + (size_t)(m0 + rA1) * D + k0 + cA1 * 8, (char*)sA + lb1);
    gload16(woh + (size_t)(n0 + rA0) * D + k0 + cA0 * 8, (char*)sB + lb0);
    gload16(woh + (size_t)(n0 + rA1) * D + k0 + cA1 * 8, (char*)sB + lb1);
    __syncthreads();
    half8 a[4], b[4];
#pragma unroll
    for (int f = 0; f < 4; ++f) {
      a[f] = *(const half8*)(sA + (wr * 64 + f * 16 + lr) * 32 + lk * 8);
      b[f] = *(const half8*)(sB + (wc * 64 + f * 16 + lr) * 32 + lk * 8);
    }
#pragma unroll
    for (int fm = 0; fm < 4; ++fm)
#pragma unroll
      for (int fn = 0; fn < 4; ++fn)
        acc[fm][fn] = __builtin_amdgcn_mfma_f32_16x16x32_f16(a[fm], b[fn], acc[fm][fn], 0, 0, 0);
    __syncthreads();
  }
#pragma unroll
  for (int fm = 0; fm < 4; ++fm)
#pragma unroll
    for (int j = 0; j < 4; ++j) {
      int row = wr * 64 + fm * 16 + lk * 4 + j;
#pragma unroll
      for (int fn = 0; fn < 4; ++fn) {
        int col = n0 + wc * 64 + fn * 16 + lr;
        F[(size_t)(m0 + row) * D + col] = acc[fm][fn][j] + b_out[col];
      }
    }
}

// ---------------- k_expand: LDS-transposed gather of F rows ----------------
__global__ __launch_bounds__(256) void k_expand(
    const float* __restrict__ F, const unsigned long long* __restrict__ keys,
    const unsigned long long* __restrict__ keys2,
    const float* __restrict__ mask, float* __restrict__ out) {
  __shared__ float ldsF[64 * 67];
  const int b = blockIdx.y;
  const int t0 = blockIdx.x * 128;
  const int ocbase = blockIdx.z * 512;
  const int tid = threadIdx.x;

  const int tok_w = tid & 63, ocr = tid >> 6;
  const float2 mv = *(const float2*)&mask[(size_t)b * TLEN + t0 + 2 * tok_w];
  float* outb = out + ((size_t)b * D) * TLEN + t0 + 2 * tok_w;

  const int ltk = tid >> 2, lg = tid & 3;
  const int lm = b * 2048 + (t0 >> 1) + ltk;
  unsigned long long kk = keys2[lm];
  if (kk == ~0ull) kk = keys[lm];
  const unsigned lidx = (unsigned)(kk & 0xFFFFFFFFull);
  const float* Fl = F + (size_t)lidx * D + lg * 16;

  for (int c8 = 0; c8 < 8; ++c8) {
    const int oc0 = ocbase + c8 * 64;
#pragma unroll
    for (int j = 0; j < 16; ++j)
      ldsF[ltk * 67 + lg * 16 + j] = Fl[oc0 + j];
    __syncthreads();
#pragma unroll
    for (int i = 0; i < 16; ++i) {
      int c = ocr + i * 4;
      float v = ldsF[tok_w * 67 + c];
      float2 o; o.x = v * mv.x; o.y = v * mv.y;
      *(float2*)&outb[(size_t)(oc0 + c) * TLEN] = o;
    }
    __syncthreads();
  }
}

// ---------------- loss ----------------
__global__ __launch_bounds__(256) void k_loss(const unsigned long long* __restrict__ keys,
                                              const unsigned long long* __restrict__ keys2,
                                              const float* __restrict__ t2,
                                              double* __restrict__ acc) {
  int m = blockIdx.x * 256 + threadIdx.x;
  unsigned long long k = keys2[m];
  if (k == ~0ull) k = keys[m];
  float mval = key_to_f32((unsigned)(k >> 32));
  double c = (double)mval + 1024.0 + (double)t2[m];
#pragma unroll
  for (int mk = 1; mk < 64; mk <<= 1) c += __shfl_xor(c, mk, 64);
  __shared__ double part[4];
  if ((threadIdx.x & 63) == 0) part[threadIdx.x >> 6] = c;
  __syncthreads();
  if (threadIdx.x == 0) atomicAdd(acc, part[0] + part[1] + part[2] + part[3]);
}

__global__ void k_finalize(const double* __restrict__ acc, float* __restrict__ dst) {
  if (threadIdx.x == 0 && blockIdx.x == 0) *dst = (float)(*acc * (1.0 / 16777216.0));
}

// ---------------- host ----------------
extern "C" void kernel_launch(void* const* d_in, const int* in_sizes, int n_in,
                              void* d_out, int out_size, void* d_ws, size_t ws_size,
                              hipStream_t stream) {
  (void)in_sizes; (void)n_in; (void)out_size;
  const float* x      = (const float*)d_in[0];
  const float* xmask  = (const float*)d_in[1];
  const float* w_in   = (const float*)d_in[2];
  const float* b_in   = (const float*)d_in[3];
  const float* embed  = (const float*)d_in[4];
  const float* w_out  = (const float*)d_in[5];
  const float* b_out  = (const float*)d_in[6];
  float* out = (float*)d_out;

  // x hi/lo splits live in d_out; consumed by tok1/tok_fix, overwritten by k_expand.
  _Float16* xh = (_Float16*)d_out;
  _Float16* xl = xh + (size_t)MTOK * KIN;

  char* p = (char*)d_ws;
  auto take = [&](size_t sz) { char* r = p; p += (sz + 255) & ~(size_t)255; return r; };
  _Float16* wh    = (_Float16*)take((size_t)D * KIN * 2);
  _Float16* wl    = (_Float16*)take((size_t)D * KIN * 2);
  _Float16* eh    = (_Float16*)take((size_t)NCODE * D * 2);
  _Float16* el    = (_Float16*)take((size_t)NCODE * D * 2);
  _Float16* woh   = (_Float16*)take((size_t)D * D * 2);
  float* Fm       = (float*)take((size_t)NCODE * D * 4);
  float* e2c      = (float*)take((size_t)NCODE * 4);
  _Float16* tokh  = (_Float16*)take((size_t)MTOK * D * 2);
  _Float16* tokh2 = (_Float16*)take((size_t)CAP * D * 2);
  _Float16* tokl2 = (_Float16*)take((size_t)CAP * D * 2);
  float* t2       = (float*)take((size_t)MTOK * 4);
  unsigned long long* keys  = (unsigned long long*)take((size_t)MTOK * 8);
  unsigned long long* keys2 = (unsigned long long*)take((size_t)MTOK * 8);
  unsigned long long* skKey = (unsigned long long*)take((size_t)MTOK * 32 * 8);
  float* skSnd    = (float*)take((size_t)MTOK * 32 * 4);
  int* list       = (int*)take((size_t)CAP * 4);
  int* counter    = (int*)take(256);
  double* lossacc = (double*)take(256);
  if ((size_t)(p - (char*)d_ws) > ws_size) return;

  k_pack_x<<<dim3(64, 32, 8), 256, 0, stream>>>(x, xh, xl);
  k_split3<<<(D * KIN + NCODE * D + D * D + 255) / 256, 256, 0, stream>>>(
      w_in, embed, w_out, wh, wl, eh, el, woh);
  k_e2<<<NCODE / 4, 256, 0, stream>>>(embed, e2c, counter, lossacc, t2);

  // F = embed . w_out^T + b_out (hh-only single-product GEMM)
  k_F<<<dim3(D / 128, NCODE / 128), 256, 0, stream>>>(eh, woh, b_out, Fm);

  // tok1: hh-only tokens + t2 (256^2 tiles -> 64x4 = 256 blocks)
  k_gemm_hh<KIN, 2, 0><<<256, 512, 0, stream>>>(xh, wh, b_in, tokh, t2, nullptr, nullptr);
  // score1: hh-only scores + top-2 (64x8 = 512 blocks)
  k_gemm_hh<D, 3, 1><<<512, 512, 0, stream>>>(tokh, eh, e2c, nullptr, nullptr, skKey, skSnd);
  k_flag<<<MTOK / 256, 256, 0, stream>>>(skKey, skSnd, keys, keys2, list, counter);
  k_tok_fix<<<dim3(D / 128, CAP / 128), 256, 0, stream>>>(xh, xl, wh, wl, b_in, list, counter, tokh2, tokl2);
  k_rescore<<<dim3(NCODE / 128, CAP / 128), 256, 0, stream>>>(tokh2, tokl2, eh, el, e2c, list, counter, keys2);

  // conv_out as transposed gather of F rows (after tok_fix — overwrites xh/xl in d_out)
  k_expand<<<dim3(TLEN / 128, 8, 2), 256, 0, stream>>>(Fm, keys, keys2, xmask, out);

  k_loss<<<MTOK / 256, 256, 0, stream>>>(keys, keys2, t2, lossacc);
  k_finalize<<<1, 64, 0, stream>>>(lossacc, out + (size_t)MTOK * KIN);
}

// Round 16
// 417.319 us; speedup vs baseline: 1.0062x; 1.0062x over previous
//
#include <hip/hip_runtime.h>

typedef _Float16 half8 __attribute__((ext_vector_type(8)));
typedef float f32x4 __attribute__((ext_vector_type(4)));

static constexpr int D = 1024;       // VQ_C == C_IN
static constexpr int NCODE = 2048;   // codebook size
static constexpr int MTOK = 16384;   // B * L = 8 * 2048
static constexpr int KIN = 2048;     // C_IN * DS
static constexpr int TLEN = 4096;
static constexpr int CAP = 2048;     // max rescored tokens (est. ~250 flagged)
#define TAU 0.4f

__device__ __forceinline__ void gload16(const void* g, void* l) {
  __builtin_amdgcn_global_load_lds(
      (const __attribute__((address_space(1))) void*)g,
      (__attribute__((address_space(3))) void*)l, 16, 0, 0);
}

#define SBAR()   asm volatile("s_barrier" ::: "memory")
#define WAITV4() asm volatile("s_waitcnt vmcnt(4)" ::: "memory")
#define WAITV0() asm volatile("s_waitcnt vmcnt(0)" ::: "memory")

__device__ __forceinline__ float key_to_f32(unsigned u) {
  unsigned bits = (u & 0x80000000u) ? (u & 0x7FFFFFFFu) : ~u;
  return __uint_as_float(bits);
}
__device__ __forceinline__ unsigned f32_to_key(float f) {
  unsigned ub = __float_as_uint(f);
  return (ub & 0x80000000u) ? ~ub : (ub | 0x80000000u);
}

// ---------------- pack kernels ----------------
__global__ __launch_bounds__(256) void k_pack_x(const float* __restrict__ x,
                                                _Float16* __restrict__ xh,
                                                _Float16* __restrict__ xl) {
  __shared__ float lds[32][65];
  const int tt0 = blockIdx.x * 64;
  const int cc0 = blockIdx.y * 32;
  const int b = blockIdx.z;
  const float* xb = x + ((size_t)b * D + cc0) * TLEN + tt0;
#pragma unroll
  for (int i = 0; i < 8; ++i) {
    int idx = threadIdx.x + i * 256;
    lds[idx >> 6][idx & 63] = xb[(size_t)(idx >> 6) * TLEN + (idx & 63)];
  }
  __syncthreads();
  const size_t mrow0 = (size_t)b * 2048 + (tt0 >> 1);
  const int r = threadIdx.x >> 3;
  const int g = threadIdx.x & 7;
  half8 vh, vl;
#pragma unroll
  for (int j = 0; j < 8; ++j) {
    int kk = g * 8 + j;
    float v = lds[kk >> 1][2 * r + (kk & 1)];
    _Float16 h = (_Float16)v;
    vh[j] = h;
    vl[j] = (_Float16)(v - (float)h);
  }
  size_t off = (mrow0 + r) * (size_t)KIN + (size_t)cc0 * 2 + g * 8;
  *(half8*)(xh + off) = vh;
  *(half8*)(xl + off) = vl;
}

// merged splitter: w_in -> wh/wl, embed -> eh/el, w_out -> woh (hi only)
__global__ __launch_bounds__(256) void k_split3(
    const float* __restrict__ w_in, const float* __restrict__ embed,
    const float* __restrict__ w_out,
    _Float16* __restrict__ wh, _Float16* __restrict__ wl,
    _Float16* __restrict__ eh, _Float16* __restrict__ el,
    _Float16* __restrict__ woh) {
  int i = blockIdx.x * 256 + threadIdx.x;
  if (i < D * KIN) {
    float v = w_in[i];
    _Float16 h = (_Float16)v;
    wh[i] = h;
    wl[i] = (_Float16)(v - (float)h);
  } else if (i < D * KIN + NCODE * D) {
    int j = i - D * KIN;
    float v = embed[j];
    _Float16 h = (_Float16)v;
    eh[j] = h;
    el[j] = (_Float16)(v - (float)h);
  } else if (i < D * KIN + NCODE * D + D * D) {
    int j = i - D * KIN - NCODE * D;
    woh[j] = (_Float16)w_out[j];
  }
}

// e2 + fold zero-inits (counter, lossacc, t2)
__global__ __launch_bounds__(256) void k_e2(const float* __restrict__ embed,
                                            float* __restrict__ e2c,
                                            int* __restrict__ counter,
                                            double* __restrict__ lossacc,
                                            float* __restrict__ t2) {
  if (blockIdx.x == 0 && threadIdx.x == 0) { counter[0] = 0; lossacc[0] = 0.0; }
  int g = blockIdx.x * 256 + threadIdx.x;
  if (g < MTOK) t2[g] = 0.f;
  int row = blockIdx.x * 4 + (threadIdx.x >> 6);
  int lane = threadIdx.x & 63;
  const float* er = embed + (size_t)row * D;
  double s = 0.0;
  for (int i = lane; i < D; i += 64) { double v = er[i]; s += v * v; }
#pragma unroll
  for (int mk = 1; mk < 64; mk <<= 1) s += __shfl_xor(s, mk, 64);
  if (lane == 0) e2c[row] = (float)(s - 1024.0);
}

// ---------------- hh GEMM: 256x256 tile, 512 thr, 8 waves (2x4), 3-buf (R8/R14-proven) ----
// MODE 0: tok epilogue (bias, f16 hi store, ||t||^2 atomics).  MODE 1: score top-2.
template <int KDIM, int LOG_GX, int MODE>
__global__ __launch_bounds__(512, 2) void k_gemm_hh(
    const _Float16* __restrict__ Ah_, const _Float16* __restrict__ Bh_,
    const float* __restrict__ vec,
    _Float16* __restrict__ outh, float* __restrict__ t2,
    unsigned long long* __restrict__ skKey, float* __restrict__ skSnd) {
  __shared__ _Float16 lds[3 * 16384];  // 3 x 32KB
  const int nwg = gridDim.x, bid = blockIdx.x, q = nwg >> 3;
  const int b2 = (bid & 7) * q + (bid >> 3);
  const int nb = b2 & ((1 << LOG_GX) - 1);
  const int n0 = nb * 256, m0 = (b2 >> LOG_GX) * 256;
  const int tid = threadIdx.x, lane = tid & 63, w = tid >> 6;
  const int wr = w >> 2, wc = w & 3, lr = lane & 15, lk = lane >> 4;
  constexpr int NT = KDIM / 32;
  const int cswz8 = (((lane & 3) ^ ((lane >> 3) & 3))) * 8;
  const int rswz8 = (lk ^ ((lr >> 1) & 3)) * 8;

  f32x4 acc[8][4] = {};

  auto stage = [&](int t, int c) {  // 4 loads/thread = 32KB/block
    char* sb = (char*)(lds + c * 16384);
    const int k0 = t * 32;
    const int r0 = (w * 64 + lane) >> 2;
    gload16(Ah_ + (size_t)(m0 + r0) * KDIM + k0 + cswz8, sb + w * 1024);
    gload16(Ah_ + (size_t)(m0 + 128 + r0) * KDIM + k0 + cswz8, sb + w * 1024 + 8192);
    gload16(Bh_ + (size_t)(n0 + r0) * KDIM + k0 + cswz8, sb + 16384 + w * 1024);
    gload16(Bh_ + (size_t)(n0 + 128 + r0) * KDIM + k0 + cswz8, sb + 16384 + w * 1024 + 8192);
  };

  stage(0, 0);
  stage(1, 1);
  WAITV4();
  SBAR();

  int c0 = 0, c1 = 1, c2 = 2;
  for (int t = 0; t < NT; ++t) {
    const bool st = (t + 2) < NT;
    if (st) stage(t + 2, c2);
    const _Float16* sb = lds + c0 * 16384;
    half8 ah[8], bh[4];
#pragma unroll
    for (int f = 0; f < 8; ++f)
      ah[f] = *(const half8*)(sb + (wr * 128 + f * 16 + lr) * 32 + rswz8);
#pragma unroll
    for (int f = 0; f < 4; ++f)
      bh[f] = *(const half8*)(sb + 8192 + (wc * 64 + f * 16 + lr) * 32 + rswz8);
    __builtin_amdgcn_s_setprio(1);
#pragma unroll
    for (int fm = 0; fm < 8; ++fm)
#pragma unroll
      for (int fn = 0; fn < 4; ++fn)
        acc[fm][fn] = __builtin_amdgcn_mfma_f32_16x16x32_f16(ah[fm], bh[fn], acc[fm][fn], 0, 0, 0);
    __builtin_amdgcn_s_setprio(0);
    if (st) { WAITV4(); } else if (t + 1 < NT) { WAITV0(); }
    SBAR();
    int tmp = c0; c0 = c1; c1 = c2; c2 = tmp;
  }

  if constexpr (MODE == 0) {
    // tok epilogue: +bias, store f16 hi, accumulate ||t||^2
#pragma unroll
    for (int fm = 0; fm < 8; ++fm) {
#pragma unroll
      for (int j = 0; j < 4; ++j) {
        int row = wr * 128 + fm * 16 + lk * 4 + j;
        size_t m = (size_t)m0 + row;
        float v2 = 0.f;
#pragma unroll
        for (int fn = 0; fn < 4; ++fn) {
          int col = n0 + wc * 64 + fn * 16 + lr;
          float v = acc[fm][fn][j] + vec[col];
          v2 += v * v;
          outh[m * (size_t)D + col] = (_Float16)v;
        }
#pragma unroll
        for (int mk = 1; mk < 16; mk <<= 1) v2 += __shfl_xor(v2, mk, 64);
        if (lr == 0) atomicAdd(&t2[m], v2);
      }
    }
  } else {
    // score epilogue: top-2 of mval over this wave's 64 codes -> slot nb*4+wc
#pragma unroll
    for (int fm = 0; fm < 8; ++fm) {
#pragma unroll
      for (int j = 0; j < 4; ++j) {
        int row = wr * 128 + fm * 16 + lk * 4 + j;
        size_t m = (size_t)m0 + row;
        float b1 = 3.4e38f, bb2 = 3.4e38f;
        int i1 = 0x7FFFFFFF;
#pragma unroll
        for (int fn = 0; fn < 4; ++fn) {
          int col = n0 + wc * 64 + fn * 16 + lr;
          float mv = vec[col] - 2.0f * acc[fm][fn][j];
          if (mv < b1) { bb2 = b1; b1 = mv; i1 = col; }
          else if (mv < bb2) { bb2 = mv; }
        }
#pragma unroll
        for (int mk = 1; mk < 16; mk <<= 1) {
          float ob1 = __shfl_xor(b1, mk, 64);
          float ob2 = __shfl_xor(bb2, mk, 64);
          int oi = __shfl_xor(i1, mk, 64);
          if (ob1 < b1) { bb2 = fminf(b1, ob2); b1 = ob1; i1 = oi; }
          else { bb2 = fminf(bb2, ob1); }
        }
        if (lr == 0) {
          unsigned long long key = ((unsigned long long)f32_to_key(b1) << 32) | (unsigned)i1;
          skKey[m * 32 + nb * 4 + wc] = key;
          skSnd[m * 32 + nb * 4 + wc] = bb2;
        }
      }
    }
  }
}

// ---------------- flag: global top-2 over 32 slots; also init keys2 ----------------
__global__ __launch_bounds__(256) void k_flag(const unsigned long long* __restrict__ skKey,
                                              const float* __restrict__ skSnd,
                                              unsigned long long* __restrict__ keys,
                                              unsigned long long* __restrict__ keys2,
                                              int* __restrict__ list, int* __restrict__ counter) {
  int m = blockIdx.x * 256 + threadIdx.x;
  keys2[m] = ~0ull;
  unsigned long long best = ~0ull;
  int bsl = 0;
#pragma unroll
  for (int sl = 0; sl < 32; ++sl) {
    unsigned long long k = skKey[(size_t)m * 32 + sl];
    if (k < best) { best = k; bsl = sl; }
  }
  float b1 = key_to_f32((unsigned)(best >> 32));
  float second = skSnd[(size_t)m * 32 + bsl];
#pragma unroll
  for (int sl = 0; sl < 32; ++sl) {
    if (sl != bsl) second = fminf(second, key_to_f32((unsigned)(skKey[(size_t)m * 32 + sl] >> 32)));
  }
  keys[m] = best;
  if (second - b1 < TAU) {
    int p = atomicAdd(counter, 1);
    if (p < CAP) list[p] = m;
  }
}

// ---------------- tok_fix: recompute TRUE tokens (3-product) for flagged rows ----------------
__global__ __launch_bounds__(256) void k_tok_fix(
    const _Float16* __restrict__ xh, const _Float16* __restrict__ xl,
    const _Float16* __restrict__ wh, const _Float16* __restrict__ wl,
    const float* __restrict__ b_in, const int* __restrict__ list,
    const int* __restrict__ counter,
    _Float16* __restrict__ tokh2, _Float16* __restrict__ tokl2) {
  const int count = min(counter[0], CAP);
  const int m0 = blockIdx.y * 128;
  if (m0 >= count) return;
  __shared__ _Float16 sAh[128 * 32], sAl[128 * 32], sBh[128 * 32], sBl[128 * 32];
  const int n0 = blockIdx.x * 128;
  const int tid = threadIdx.x, lane = tid & 63, w = tid >> 6;
  const int wr = w >> 1, wc = w & 1, lr = lane & 15, lk = lane >> 4;
  f32x4 acc[4][4] = {};

  const int g0 = w * 128 + lane, g1 = g0 + 64;
  const int rA0 = g0 >> 2, cA0 = g0 & 3, rA1 = g1 >> 2, cA1 = g1 & 3;
  const int lb0 = (w * 128) * 16, lb1 = (w * 128 + 64) * 16;
  const int tk0 = list[min(m0 + rA0, count - 1)];
  const int tk1 = list[min(m0 + rA1, count - 1)];

  for (int kt = 0; kt < KIN / 32; ++kt) {
    const int k0 = kt * 32;
    gload16(xh + (size_t)tk0 * KIN + k0 + cA0 * 8, (char*)sAh + lb0);
    gload16(xh + (size_t)tk1 * KIN + k0 + cA1 * 8, (char*)sAh + lb1);
    gload16(xl + (size_t)tk0 * KIN + k0 + cA0 * 8, (char*)sAl + lb0);
    gload16(xl + (size_t)tk1 * KIN + k0 + cA1 * 8, (char*)sAl + lb1);
    gload16(wh + (size_t)(n0 + rA0) * KIN + k0 + cA0 * 8, (char*)sBh + lb0);
    gload16(wh + (size_t)(n0 + rA1) * KIN + k0 + cA1 * 8, (char*)sBh + lb1);
    gload16(wl + (size_t)(n0 + rA0) * KIN + k0 + cA0 * 8, (char*)sBl + lb0);
    gload16(wl + (size_t)(n0 + rA1) * KIN + k0 + cA1 * 8, (char*)sBl + lb1);
    __syncthreads();
    half8 ah[4], al2[4], bh[4], bl2[4];
#pragma unroll
    for (int f = 0; f < 4; ++f) {
      ah[f]  = *(const half8*)(sAh + (wr * 64 + f * 16 + lr) * 32 + lk * 8);
      al2[f] = *(const half8*)(sAl + (wr * 64 + f * 16 + lr) * 32 + lk * 8);
      bh[f]  = *(const half8*)(sBh + (wc * 64 + f * 16 + lr) * 32 + lk * 8);
      bl2[f] = *(const half8*)(sBl + (wc * 64 + f * 16 + lr) * 32 + lk * 8);
    }
#pragma unroll
    for (int fm = 0; fm < 4; ++fm)
#pragma unroll
      for (int fn = 0; fn < 4; ++fn) {
        acc[fm][fn] = __builtin_amdgcn_mfma_f32_16x16x32_f16(ah[fm], bh[fn], acc[fm][fn], 0, 0, 0);
        acc[fm][fn] = __builtin_amdgcn_mfma_f32_16x16x32_f16(ah[fm], bl2[fn], acc[fm][fn], 0, 0, 0);
        acc[fm][fn] = __builtin_amdgcn_mfma_f32_16x16x32_f16(al2[fm], bh[fn], acc[fm][fn], 0, 0, 0);
      }
    __syncthreads();
  }
#pragma unroll
  for (int fm = 0; fm < 4; ++fm) {
#pragma unroll
    for (int j = 0; j < 4; ++j) {
      int row = wr * 64 + fm * 16 + lk * 4 + j;
      if (m0 + row >= count) continue;
#pragma unroll
      for (int fn = 0; fn < 4; ++fn) {
        int col = n0 + wc * 64 + fn * 16 + lr;
        float v = acc[fm][fn][j] + b_in[col];
        _Float16 h = (_Float16)v;
        tokh2[(size_t)(m0 + row) * D + col] = h;
        tokl2[(size_t)(m0 + row) * D + col] = (_Float16)(v - (float)h);
      }
    }
  }
}

// ---------------- rescore: 3-product exact scoring of flagged tokens ----------------
__global__ __launch_bounds__(256) void k_rescore(
    const _Float16* __restrict__ tokh2, const _Float16* __restrict__ tokl2,
    const _Float16* __restrict__ eh, const _Float16* __restrict__ el,
    const float* __restrict__ e2c, const int* __restrict__ list,
    const int* __restrict__ counter,
    unsigned long long* __restrict__ keys2) {
  const int count = min(counter[0], CAP);
  const int m0 = blockIdx.y * 128;
  if (m0 >= count) return;
  __shared__ _Float16 sAh[128 * 32], sAl[128 * 32], sBh[128 * 32], sBl[128 * 32];
  const int n0 = blockIdx.x * 128;
  const int tid = threadIdx.x, lane = tid & 63, w = tid >> 6;
  const int wr = w >> 1, wc = w & 1, lr = lane & 15, lk = lane >> 4;
  f32x4 acc[4][4] = {};

  const int g0 = w * 128 + lane, g1 = g0 + 64;
  const int rA0 = g0 >> 2, cA0 = g0 & 3, rA1 = g1 >> 2, cA1 = g1 & 3;
  const int lb0 = (w * 128) * 16, lb1 = (w * 128 + 64) * 16;

  for (int kt = 0; kt < D / 32; ++kt) {
    const int k0 = kt * 32;
    gload16(tokh2 + (size_t)(m0 + rA0) * D + k0 + cA0 * 8, (char*)sAh + lb0);
    gload16(tokh2 + (size_t)(m0 + rA1) * D + k0 + cA1 * 8, (char*)sAh + lb1);
    gload16(tokl2 + (size_t)(m0 + rA0) * D + k0 + cA0 * 8, (char*)sAl + lb0);
    gload16(tokl2 + (size_t)(m0 + rA1) * D + k0 + cA1 * 8, (char*)sAl + lb1);
    gload16(eh + (size_t)(n0 + rA0) * D + k0 + cA0 * 8, (char*)sBh + lb0);
    gload16(eh + (size_t)(n0 + rA1) * D + k0 + cA1 * 8, (char*)sBh + lb1);
    gload16(el + (size_t)(n0 + rA0) * D + k0 + cA0 * 8, (char*)sBl + lb0);
    gload16(el + (size_t)(n0 + rA1) * D + k0 + cA1 * 8, (char*)sBl + lb1);
    __syncthreads();
    half8 ah[4], al2[4], bh[4], bl2[4];
#pragma unroll
    for (int f = 0; f < 4; ++f) {
      ah[f]  = *(const half8*)(sAh + (wr * 64 + f * 16 + lr) * 32 + lk * 8);
      al2[f] = *(const half8*)(sAl + (wr * 64 + f * 16 + lr) * 32 + lk * 8);
      bh[f]  = *(const half8*)(sBh + (wc * 64 + f * 16 + lr) * 32 + lk * 8);
      bl2[f] = *(const half8*)(sBl + (wc * 64 + f * 16 + lr) * 32 + lk * 8);
    }
#pragma unroll
    for (int fm = 0; fm < 4; ++fm)
#pragma unroll
      for (int fn = 0; fn < 4; ++fn) {
        acc[fm][fn] = __builtin_amdgcn_mfma_f32_16x16x32_f16(ah[fm], bh[fn], acc[fm][fn], 0, 0, 0);
        acc[fm][fn] = __builtin_amdgcn_mfma_f32_16x16x32_f16(ah[fm], bl2[fn], acc[fm][fn], 0, 0, 0);
        acc[fm][fn] = __builtin_amdgcn_mfma_f32_16x16x32_f16(al2[fm], bh[fn], acc[fm][fn], 0, 0, 0);
      }
    __syncthreads();
  }
#pragma unroll
  for (int fm = 0; fm < 4; ++fm) {
#pragma unroll
    for (int j = 0; j < 4; ++j) {
      int row = wr * 64 + fm * 16 + lk * 4 + j;
      if (m0 + row >= count) continue;
      int tm = list[m0 + row];
      float best = 3.4e38f;
      int bidx = 0x7FFFFFFF;
#pragma unroll
      for (int fn = 0; fn < 4; ++fn) {
        int col = n0 + wc * 64 + fn * 16 + lr;
        float mv = e2c[col] - 2.0f * acc[fm][fn][j];
        if (mv < best) { best = mv; bidx = col; }
      }
#pragma unroll
      for (int mk = 1; mk < 16; mk <<= 1) {
        float ob = __shfl_xor(best, mk, 64);
        int oi = __shfl_xor(bidx, mk, 64);
        if (ob < best || (ob == best && oi < bidx)) { best = ob; bidx = oi; }
      }
      if (lr == 0) {
        unsigned long long key = ((unsigned long long)f32_to_key(best) << 32) | (unsigned)bidx;
        atomicMin(&keys2[tm], key);
      }
    }
  }
}

// ---------------- k_F: F = embed . w_out^T + b_out (hh-only) ----------------
__global__ __launch_bounds__(256) void k_F(
    const _Float16* __restrict__ eh, const _Float16* __restrict__ woh,
    const float* __restrict__ b_out, float* __restrict__ F) {
  __shared__ _Float16 sA[128 * 32], sB[128 * 32];
  const int n0 = blockIdx.x * 128, m0 = blockIdx.y * 128;
  const int tid = threadIdx.x, lane = tid & 63, w = tid >> 6;
  const int wr = w >> 1, wc = w & 1, lr = lane & 15, lk = lane >> 4;
  f32x4 acc[4][4] = {};

  const int g0 = w * 128 + lane, g1 = g0 + 64;
  const int rA0 = g0 >> 2, cA0 = g0 & 3, rA1 = g1 >> 2, cA1 = g1 & 3;
  const int lb0 = (w * 128) * 16, lb1 = (w * 128 + 64) * 16;

  for (int kt = 0; kt < D / 32; ++kt) {
    const int k0 = kt * 32;
    gload16(eh + (size_t)(m0 + rA0) * D + k0 + cA0 * 8, (char*)sA + lb0);
    gload16(eh + (size_t)(m0 + rA1) * D + k0 + cA1 * 8, (char*)sA + lb1);
    gload16(woh + (size_t)(n0 + rA0) * D + k0 + cA0 * 8, (char*)sB + lb0);
    gload16(woh + (size_t)(n0 + rA1) * D + k0 + cA1 * 8, (char*)sB + lb1);
    __syncthreads();
    half8 a[4], b[4];
#pragma unroll
    for (int f = 0; f < 4; ++f) {
      a[f] = *(const half8*)(sA + (wr * 64 + f * 16 + lr) * 32 + lk * 8);
      b[f] = *(const half8*)(sB + (wc * 64 + f * 16 + lr) * 32 + lk * 8);
    }
#pragma unroll
    for (int fm = 0; fm < 4; ++fm)
#pragma unroll
      for (int fn = 0; fn < 4; ++fn)
        acc[fm][fn] = __builtin_amdgcn_mfma_f32_16x16x32_f16(a[fm], b[fn], acc[fm][fn], 0, 0, 0);
    __syncthreads();
  }
#pragma unroll
  for (int fm = 0; fm < 4; ++fm)
#pragma unroll
    for (int j = 0; j < 4; ++j) {
      int row = wr * 64 + fm * 16 + lk * 4 + j;
#pragma unroll
      for (int fn = 0; fn < 4; ++fn) {
        int col = n0 + wc * 64 + fn * 16 + lr;
        F[(size_t)(m0 + row) * D + col] = acc[fm][fn][j] + b_out[col];
      }
    }
}

// ---------------- k_expand: LDS-transposed gather of F rows ----------------
__global__ __launch_bounds__(256) void k_expand(
    const float* __restrict__ F, const unsigned long long* __restrict__ keys,
    const unsigned long long* __restrict__ keys2,
    const float* __restrict__ mask, float* __restrict__ out) {
  __shared__ float ldsF[64 * 67];
  const int b = blockIdx.y;
  const int t0 = blockIdx.x * 128;
  const int ocbase = blockIdx.z * 512;
  const int tid = threadIdx.x;

  const int tok_w = tid & 63, ocr = tid >> 6;
  const float2 mv = *(const float2*)&mask[(size_t)b * TLEN + t0 + 2 * tok_w];
  float* outb = out + ((size_t)b * D) * TLEN + t0 + 2 * tok_w;

  const int ltk = tid >> 2, lg = tid & 3;
  const int lm = b * 2048 + (t0 >> 1) + ltk;
  unsigned long long kk = keys2[lm];
  if (kk == ~0ull) kk = keys[lm];
  const unsigned lidx = (unsigned)(kk & 0xFFFFFFFFull);
  const float* Fl = F + (size_t)lidx * D + lg * 16;

  for (int c8 = 0; c8 < 8; ++c8) {
    const int oc0 = ocbase + c8 * 64;
#pragma unroll
    for (int j = 0; j < 16; ++j)
      ldsF[ltk * 67 + lg * 16 + j] = Fl[oc0 + j];
    __syncthreads();
#pragma unroll
    for (int i = 0; i < 16; ++i) {
      int c = ocr + i * 4;
      float v = ldsF[tok_w * 67 + c];
      float2 o; o.x = v * mv.x; o.y = v * mv.y;
      *(float2*)&outb[(size_t)(oc0 + c) * TLEN] = o;
    }
    __syncthreads();
  }
}

// ---------------- loss ----------------
__global__ __launch_bounds__(256) void k_loss(const unsigned long long* __restrict__ keys,
                                              const unsigned long long* __restrict__ keys2,
                                              const float* __restrict__ t2,
                                              double* __restrict__ acc) {
  int m = blockIdx.x * 256 + threadIdx.x;
  unsigned long long k = keys2[m];
  if (k == ~0ull) k = keys[m];
  float mval = key_to_f32((unsigned)(k >> 32));
  double c = (double)mval + 1024.0 + (double)t2[m];
#pragma unroll
  for (int mk = 1; mk < 64; mk <<= 1) c += __shfl_xor(c, mk, 64);
  __shared__ double part[4];
  if ((threadIdx.x & 63) == 0) part[threadIdx.x >> 6] = c;
  __syncthreads();
  if (threadIdx.x == 0) atomicAdd(acc, part[0] + part[1] + part[2] + part[3]);
}

__global__ void k_finalize(const double* __restrict__ acc, float* __restrict__ dst) {
  if (threadIdx.x == 0 && blockIdx.x == 0) *dst = (float)(*acc * (1.0 / 16777216.0));
}

// ---------------- host ----------------
extern "C" void kernel_launch(void* const* d_in, const int* in_sizes, int n_in,
                              void* d_out, int out_size, void* d_ws, size_t ws_size,
                              hipStream_t stream) {
  (void)in_sizes; (void)n_in; (void)out_size;
  const float* x      = (const float*)d_in[0];
  const float* xmask  = (const float*)d_in[1];
  const float* w_in   = (const float*)d_in[2];
  const float* b_in   = (const float*)d_in[3];
  const float* embed  = (const float*)d_in[4];
  const float* w_out  = (const float*)d_in[5];
  const float* b_out  = (const float*)d_in[6];
  float* out = (float*)d_out;

  // x hi/lo splits live in d_out; consumed by tok1/tok_fix, overwritten by k_expand.
  _Float16* xh = (_Float16*)d_out;
  _Float16* xl = xh + (size_t)MTOK * KIN;

  char* p = (char*)d_ws;
  auto take = [&](size_t sz) { char* r = p; p += (sz + 255) & ~(size_t)255; return r; };
  _Float16* wh    = (_Float16*)take((size_t)D * KIN * 2);
  _Float16* wl    = (_Float16*)take((size_t)D * KIN * 2);
  _Float16* eh    = (_Float16*)take((size_t)NCODE * D * 2);
  _Float16* el    = (_Float16*)take((size_t)NCODE * D * 2);
  _Float16* woh   = (_Float16*)take((size_t)D * D * 2);
  float* Fm       = (float*)take((size_t)NCODE * D * 4);
  float* e2c      = (float*)take((size_t)NCODE * 4);
  _Float16* tokh  = (_Float16*)take((size_t)MTOK * D * 2);
  _Float16* tokh2 = (_Float16*)take((size_t)CAP * D * 2);
  _Float16* tokl2 = (_Float16*)take((size_t)CAP * D * 2);
  float* t2       = (float*)take((size_t)MTOK * 4);
  unsigned long long* keys  = (unsigned long long*)take((size_t)MTOK * 8);
  unsigned long long* keys2 = (unsigned long long*)take((size_t)MTOK * 8);
  unsigned long long* skKey = (unsigned long long*)take((size_t)MTOK * 32 * 8);
  float* skSnd    = (float*)take((size_t)MTOK * 32 * 4);
  int* list       = (int*)take((size_t)CAP * 4);
  int* counter    = (int*)take(256);
  double* lossacc = (double*)take(256);
  if ((size_t)(p - (char*)d_ws) > ws_size) return;

  k_pack_x<<<dim3(64, 32, 8), 256, 0, stream>>>(x, xh, xl);
  k_split3<<<(D * KIN + NCODE * D + D * D + 255) / 256, 256, 0, stream>>>(
      w_in, embed, w_out, wh, wl, eh, el, woh);
  k_e2<<<NCODE / 4, 256, 0, stream>>>(embed, e2c, counter, lossacc, t2);

  // F = embed . w_out^T + b_out (hh-only single-product GEMM)
  k_F<<<dim3(D / 128, NCODE / 128), 256, 0, stream>>>(eh, woh, b_out, Fm);

  // tok1: hh-only tokens + t2 (256^2 tiles -> 64x4 = 256 blocks)
  k_gemm_hh<KIN, 2, 0><<<256, 512, 0, stream>>>(xh, wh, b_in, tokh, t2, nullptr, nullptr);
  // score1: hh-only scores + top-2 (64x8 = 512 blocks)
  k_gemm_hh<D, 3, 1><<<512, 512, 0, stream>>>(tokh, eh, e2c, nullptr, nullptr, skKey, skSnd);
  k_flag<<<MTOK / 256, 256, 0, stream>>>(skKey, skSnd, keys, keys2, list, counter);
  k_tok_fix<<<dim3(D / 128, CAP / 128), 256, 0, stream>>>(xh, xl, wh, wl, b_in, list, counter, tokh2, tokl2);
  k_rescore<<<dim3(NCODE / 128, CAP / 128), 256, 0, stream>>>(tokh2, tokl2, eh, el, e2c, list, counter, keys2);

  // conv_out as transposed gather of F rows (after tok_fix — overwrites xh/xl in d_out)
  k_expand<<<dim3(TLEN / 128, 8, 2), 256, 0, stream>>>(Fm, keys, keys2, xmask, out);

  k_loss<<<MTOK / 256, 256, 0, stream>>>(keys, keys2, t2, lossacc);
  k_finalize<<<1, 64, 0, stream>>>(lossacc, out + (size_t)MTOK * KIN);
}